// Round 5
// baseline (382.838 us; speedup 1.0000x reference)
//
#include <hip/hip_runtime.h>
#include <hip/hip_bf16.h>
#include <math.h>

// Problem constants
#define B 8
#define C 512
#define H 64
#define W 64
#define N 32768     // B*H*W tokens
#define K 1024      // clusters
#define HW 4096     // H*W
#define CHW 2097152 // C*H*W
#define S 8         // esum splits (== batch)

typedef unsigned short u16;
typedef __attribute__((ext_vector_type(4))) float f32x4;
typedef __attribute__((ext_vector_type(8))) short bf16x8;

// ws layout (float offsets)
#define MNB_OFF   0                      // K*C u16: bf16 normalized codebook [j][c]
#define IDX_OFF   (MNB_OFF + K*C/2)      // N ints: argmax
#define CNT_OFF   (IDX_OFF + N)          // K floats: counts
#define ESUMT_OFF (CNT_OFF + K)          // C*K floats: esum transposed [c][k]
#define NMT_OFF   (ESUMT_OFF + C*K)      // C*K u16: bf16 new_m transposed [c][j]
#define SCORE_OFF (NMT_OFF + C*K/2)      // N*K u16: bf16 score, then P in-place

static __device__ __forceinline__ u16 f2bf(float f) {
    unsigned int u = __float_as_uint(f);
    u += 0x7fffu + ((u >> 16) & 1u);   // RNE
    return (u16)(u >> 16);
}
static __device__ __forceinline__ float bf2f(unsigned int us) {
    return __uint_as_float(us << 16);
}
static __device__ __forceinline__ unsigned int pack2(float lo, float hi) {
    return (unsigned int)f2bf(lo) | ((unsigned int)f2bf(hi) << 16);
}

static __device__ __forceinline__ void gload_lds16(const void* g, void* l) {
    __builtin_amdgcn_global_load_lds(
        (const __attribute__((address_space(1))) unsigned int*)g,
        (__attribute__((address_space(3))) unsigned int*)l, 16, 0, 0);
}

// ---- normalize codebook rows -> bf16: mnb[j][c] ----
__global__ void k_norm_mb(const float* __restrict__ m, u16* __restrict__ mnb) {
    int j = blockIdx.x;
    int lane = threadIdx.x;  // 64
    const float4* mr = (const float4*)(m + (size_t)j * C);
    float4 a = mr[lane * 2], b = mr[lane * 2 + 1];
    float ss = a.x*a.x + a.y*a.y + a.z*a.z + a.w*a.w
             + b.x*b.x + b.y*b.y + b.z*b.z + b.w*b.w;
#pragma unroll
    for (int o = 32; o >= 1; o >>= 1) ss += __shfl_xor(ss, o);
    float inv = 1.0f / fmaxf(sqrtf(ss), 1e-12f);
    uint4 pk;
    pk.x = pack2(a.x * inv, a.y * inv);
    pk.y = pack2(a.z * inv, a.w * inv);
    pk.z = pack2(b.x * inv, b.y * inv);
    pk.w = pack2(b.z * inv, b.w * inv);
    *(uint4*)(mnb + (size_t)j * C + lane * 8) = pk;
}

// ---- normalize tokens + transpose to token-major bf16: xb[n][c] ----
__global__ void __launch_bounds__(256) k_prep_x(const float* __restrict__ x,
                                                u16* __restrict__ xb) {
    int bh = blockIdx.x;           // b*64 + h
    int b = bh >> 6, h = bh & 63;
    int w  = threadIdx.x & 63;
    int wq = threadIdx.x >> 6;     // 0..3 (channel quarter)
    const float* base = x + (size_t)b * CHW + (size_t)h * W + w;
    float ss = 0.0f;
    for (int ch = wq * 128; ch < wq * 128 + 128; ++ch) {
        float v = base[(size_t)ch * HW];
        ss += v * v;
    }
    __shared__ float red[4][64];
    red[wq][w] = ss;
    __syncthreads();
    float tot = red[0][w] + red[1][w] + red[2][w] + red[3][w];
    float inv = 1.0f / fmaxf(sqrtf(tot), 1e-12f);
    size_t n = (size_t)bh * 64 + w;
    u16* orow = xb + n * C;
    for (int c8 = wq * 128; c8 < wq * 128 + 128; c8 += 8) {
        float v0 = base[(size_t)(c8+0)*HW] * inv;
        float v1 = base[(size_t)(c8+1)*HW] * inv;
        float v2 = base[(size_t)(c8+2)*HW] * inv;
        float v3 = base[(size_t)(c8+3)*HW] * inv;
        float v4 = base[(size_t)(c8+4)*HW] * inv;
        float v5 = base[(size_t)(c8+5)*HW] * inv;
        float v6 = base[(size_t)(c8+6)*HW] * inv;
        float v7 = base[(size_t)(c8+7)*HW] * inv;
        uint4 pk;
        pk.x = pack2(v0, v1); pk.y = pack2(v2, v3);
        pk.z = pack2(v4, v5); pk.w = pack2(v6, v7);
        *(uint4*)&orow[c8] = pk;
    }
}

// ---- GEMM1 (MFMA): score[n][j] = xb[n] . mnb[j], bf16 out ----
// 128x128 tile, BK=64, 4 waves (2x2), 16x16x32 bf16 MFMA, m97 2-barrier structure
__global__ void __launch_bounds__(256) k_score_mfma(
        const u16* __restrict__ xb, const u16* __restrict__ mnb,
        u16* __restrict__ score) {
    __shared__ u16 As[128 * 64];   // [row][k] linear, 128B rows
    __shared__ u16 Bs[128 * 64];
    int tid = threadIdx.x;
    int lane = tid & 63;
    int wid = tid >> 6;            // 0..3
    int wm = wid >> 1, wn = wid & 1;
    int n0 = blockIdx.x * 128;
    int j0 = blockIdx.y * 128;

    f32x4 acc[4][4] = {};

    const u16* a_src = xb + (size_t)(n0 + wid*32 + (lane>>3)) * C + (lane&7)*8;
    const u16* b_src = mnb + (size_t)(j0 + wid*32 + (lane>>3)) * C + (lane&7)*8;

    for (int k0 = 0; k0 < C; k0 += 64) {
#pragma unroll
        for (int is = 0; is < 4; ++is) {
            gload_lds16(a_src + (size_t)is*8*C + k0, As + (wid*32 + is*8)*64);
            gload_lds16(b_src + (size_t)is*8*C + k0, Bs + (wid*32 + is*8)*64);
        }
        __syncthreads();
#pragma unroll
        for (int kh = 0; kh < 2; ++kh) {
            int kk = kh * 32;
            bf16x8 av[4], bv[4];
#pragma unroll
            for (int f = 0; f < 4; ++f) {
                av[f] = *(const bf16x8*)&As[(wm*64 + f*16 + (lane&15))*64 + kk + (lane>>4)*8];
                bv[f] = *(const bf16x8*)&Bs[(wn*64 + f*16 + (lane&15))*64 + kk + (lane>>4)*8];
            }
#pragma unroll
            for (int fm = 0; fm < 4; ++fm)
#pragma unroll
                for (int fn = 0; fn < 4; ++fn)
                    acc[fm][fn] = __builtin_amdgcn_mfma_f32_16x16x32_bf16(
                        av[fm], bv[fn], acc[fm][fn], 0, 0, 0);
        }
        __syncthreads();
    }
    int crow = (lane >> 4) * 4;
    int ccol = lane & 15;
#pragma unroll
    for (int fm = 0; fm < 4; ++fm) {
#pragma unroll
        for (int fn = 0; fn < 4; ++fn) {
            size_t rbase = (size_t)(n0 + wm*64 + fm*16 + crow) * K
                         + (j0 + wn*64 + fn*16 + ccol);
#pragma unroll
            for (int r = 0; r < 4; ++r)
                score[rbase + (size_t)r * K] = f2bf(acc[fm][fn][r]);
        }
    }
}

// ---- row stats + in-place softmax: score -> P = exp(s-max)/sumexp (bf16) ----
__global__ void k_rowstats(u16* __restrict__ score,
                           int* __restrict__ idx, float* __restrict__ counts) {
    int wq = threadIdx.x >> 6, lane = threadIdx.x & 63;
    int n = blockIdx.x * 4 + wq;
    u16* row = score + (size_t)n * K;
    uint4* rp = (uint4*)(row + lane * 16);
    uint4 q0 = rp[0], q1 = rp[1];
    float vals[16];
    unsigned int ws_[8] = {q0.x, q0.y, q0.z, q0.w, q1.x, q1.y, q1.z, q1.w};
#pragma unroll
    for (int e = 0; e < 8; ++e) {
        vals[2 * e]     = bf2f(ws_[e] & 0xffffu);
        vals[2 * e + 1] = bf2f(ws_[e] >> 16);
    }
    float best = -INFINITY; int bj = 0;
#pragma unroll
    for (int e = 0; e < 16; ++e) {
        if (vals[e] > best) { best = vals[e]; bj = lane * 16 + e; }
    }
#pragma unroll
    for (int o = 32; o >= 1; o >>= 1) {
        float ov = __shfl_xor(best, o);
        int   oj = __shfl_xor(bj, o);
        if (ov > best || (ov == best && oj < bj)) { best = ov; bj = oj; }
    }
    float p[16];
    float s = 0.0f;
#pragma unroll
    for (int e = 0; e < 16; ++e) { p[e] = __expf(vals[e] - best); s += p[e]; }
#pragma unroll
    for (int o = 32; o >= 1; o >>= 1) s += __shfl_xor(s, o);
    float sinv = 1.0f / s;
    uint4 o0, o1;
    o0.x = pack2(p[0]*sinv,  p[1]*sinv);
    o0.y = pack2(p[2]*sinv,  p[3]*sinv);
    o0.z = pack2(p[4]*sinv,  p[5]*sinv);
    o0.w = pack2(p[6]*sinv,  p[7]*sinv);
    o1.x = pack2(p[8]*sinv,  p[9]*sinv);
    o1.y = pack2(p[10]*sinv, p[11]*sinv);
    o1.z = pack2(p[12]*sinv, p[13]*sinv);
    o1.w = pack2(p[14]*sinv, p[15]*sinv);
    rp[0] = o0; rp[1] = o1;
    if (lane == 0) {
        idx[n] = bj;
        atomicAdd(&counts[bj], 1.0f);
    }
}

// ---- esum partials: block (ch, s=batch) scatters its token chunk into LDS,
//      writes 4KB partial contiguously. No global atomics. ----
__global__ void __launch_bounds__(256) k_esum_part(const float* __restrict__ x,
        const int* __restrict__ idx, float* __restrict__ partial) {
    int ch = blockIdx.x;           // 0..511
    int s  = blockIdx.y;           // 0..7  == batch b
    __shared__ float part[K];
    for (int k = threadIdx.x; k < K; k += 256) part[k] = 0.0f;
    __syncthreads();
    const float* xc = x + (size_t)s * CHW + (size_t)ch * HW;
    const int*   ic = idx + s * HW;
#pragma unroll
    for (int it = 0; it < HW / 4 / 256; ++it) {     // 4 iterations
        int t4 = (it * 256 + threadIdx.x) * 4;
        float4 v = *(const float4*)(xc + t4);
        int4 id = *(const int4*)(ic + t4);
        atomicAdd(&part[id.x], v.x);
        atomicAdd(&part[id.y], v.y);
        atomicAdd(&part[id.z], v.z);
        atomicAdd(&part[id.w], v.w);
    }
    __syncthreads();
    float* prow = partial + ((size_t)s * C + ch) * K;
    for (int k = threadIdx.x; k < K; k += 256) prow[k] = part[k];
}

// ---- reduce partials -> esumT[c][k] ----
__global__ void __launch_bounds__(256) k_esum_reduce(const float* __restrict__ partial,
        float* __restrict__ esumT) {
    int c = blockIdx.x;            // 0..511
    int k4 = threadIdx.x * 4;      // 0..1020
    float4 acc = make_float4(0.f, 0.f, 0.f, 0.f);
#pragma unroll
    for (int s = 0; s < S; ++s) {
        float4 v = *(const float4*)(partial + ((size_t)s * C + c) * K + k4);
        acc.x += v.x; acc.y += v.y; acc.z += v.z; acc.w += v.w;
    }
    *(float4*)(esumT + (size_t)c * K + k4) = acc;
}

// ---- nmt[c][j] = bf16( 0.999*m[j][c] + 0.001*esumT[c][j]/(cnt[j]+eps) ) ----
// 64x64 LDS tile transpose of m; esumT read directly (already c-major)
__global__ void __launch_bounds__(256) k_newm_t(const float* __restrict__ m,
        const float* __restrict__ esumT, const float* __restrict__ counts,
        u16* __restrict__ nmt) {
    __shared__ float tile[64][65];
    __shared__ float scs[64];
    int jb = blockIdx.x * 64, cb = blockIdx.y * 64;
    int cl = threadIdx.x & 63, jq = threadIdx.x >> 6;   // jq 0..3
#pragma unroll
    for (int r = 0; r < 16; ++r) {
        int jl = jq * 16 + r;
        tile[jl][cl] = m[(size_t)(jb + jl) * C + cb + cl];
    }
    if (threadIdx.x < 64)
        scs[threadIdx.x] = 0.001f / (counts[jb + threadIdx.x] + 1e-6f);
    __syncthreads();
    int crow = threadIdx.x >> 2;        // 0..63 output c row
    int q = threadIdx.x & 3;            // j quarter (16 each)
    const float* erow = esumT + (size_t)(cb + crow) * K + jb + q * 16;
    float4 e0 = *(const float4*)(erow + 0);
    float4 e1 = *(const float4*)(erow + 4);
    float4 e2 = *(const float4*)(erow + 8);
    float4 e3 = *(const float4*)(erow + 12);
    float ev[16] = {e0.x,e0.y,e0.z,e0.w, e1.x,e1.y,e1.z,e1.w,
                    e2.x,e2.y,e2.z,e2.w, e3.x,e3.y,e3.z,e3.w};
    float v[16];
#pragma unroll
    for (int t = 0; t < 16; ++t)
        v[t] = 0.999f * tile[q*16 + t][crow] + ev[t] * scs[q*16 + t];
    uint4 lo, hi;
    lo.x = pack2(v[0], v[1]);   lo.y = pack2(v[2], v[3]);
    lo.z = pack2(v[4], v[5]);   lo.w = pack2(v[6], v[7]);
    hi.x = pack2(v[8], v[9]);   hi.y = pack2(v[10], v[11]);
    hi.z = pack2(v[12], v[13]); hi.w = pack2(v[14], v[15]);
    u16* orow = nmt + (size_t)(cb + crow) * K + jb + q * 16;
    *(uint4*)orow = lo;
    *(uint4*)(orow + 8) = hi;
}

// ---- GEMM2 (MFMA): out[n][c] = P[n] . nmt[c], fp32 NCHW store ----
__global__ void __launch_bounds__(256) k_out_mfma(
        const u16* __restrict__ P, const u16* __restrict__ nmt,
        float* __restrict__ out) {
    __shared__ u16 As[128 * 64];
    __shared__ u16 Bs[128 * 64];
    int tid = threadIdx.x;
    int lane = tid & 63;
    int wid = tid >> 6;
    int wm = wid >> 1, wn = wid & 1;
    int n0 = blockIdx.x * 128;
    int c0 = blockIdx.y * 128;

    f32x4 acc[4][4] = {};

    const u16* a_src = P   + (size_t)(n0 + wid*32 + (lane>>3)) * K + (lane&7)*8;
    const u16* b_src = nmt + (size_t)(c0 + wid*32 + (lane>>3)) * K + (lane&7)*8;

    for (int k0 = 0; k0 < K; k0 += 64) {
#pragma unroll
        for (int is = 0; is < 4; ++is) {
            gload_lds16(a_src + (size_t)is*8*K + k0, As + (wid*32 + is*8)*64);
            gload_lds16(b_src + (size_t)is*8*K + k0, Bs + (wid*32 + is*8)*64);
        }
        __syncthreads();
#pragma unroll
        for (int kh = 0; kh < 2; ++kh) {
            int kk = kh * 32;
            bf16x8 av[4], bv[4];
#pragma unroll
            for (int f = 0; f < 4; ++f) {
                av[f] = *(const bf16x8*)&As[(wm*64 + f*16 + (lane&15))*64 + kk + (lane>>4)*8];
                bv[f] = *(const bf16x8*)&Bs[(wn*64 + f*16 + (lane&15))*64 + kk + (lane>>4)*8];
            }
#pragma unroll
            for (int fm = 0; fm < 4; ++fm)
#pragma unroll
                for (int fn = 0; fn < 4; ++fn)
                    acc[fm][fn] = __builtin_amdgcn_mfma_f32_16x16x32_bf16(
                        av[fm], bv[fn], acc[fm][fn], 0, 0, 0);
        }
        __syncthreads();
    }
    int b = n0 >> 12;
    int hw0 = (n0 & 4095) + wm * 64;
    int crow = (lane >> 4) * 4;
    int ccol = lane & 15;
    float* obase = out + (size_t)b * CHW;
#pragma unroll
    for (int fm = 0; fm < 4; ++fm) {
#pragma unroll
        for (int fn = 0; fn < 4; ++fn) {
            int ch = c0 + wn * 64 + fn * 16 + ccol;
            int hw = hw0 + fm * 16 + crow;
            float4 v = make_float4(acc[fm][fn][0], acc[fm][fn][1],
                                   acc[fm][fn][2], acc[fm][fn][3]);
            *(float4*)&obase[(size_t)ch * HW + hw] = v;
        }
    }
}

extern "C" void kernel_launch(void* const* d_in, const int* in_sizes, int n_in,
                              void* d_out, int out_size, void* d_ws, size_t ws_size,
                              hipStream_t stream) {
    const float* x = (const float*)d_in[0];
    const float* m = (const float*)d_in[1];
    float* out = (float*)d_out;
    float* ws = (float*)d_ws;

    u16*   mnb   = (u16*)(ws + MNB_OFF);
    int*   idx   = (int*)(ws + IDX_OFF);
    float* cnt   = ws + CNT_OFF;
    float* esumT = ws + ESUMT_OFF;
    u16*   nmt   = (u16*)(ws + NMT_OFF);
    u16*   score = (u16*)(ws + SCORE_OFF);
    // d_out scratch: xb (bf16 [N][C], 32MB) in [0,32MB); esum partials (16MB)
    // in [32MB,48MB). Both dead before k_out_mfma fully rewrites d_out.
    u16*   xb      = (u16*)d_out;
    float* partial = (float*)((char*)d_out + (size_t)32 * 1024 * 1024);

    hipMemsetAsync(cnt, 0, (size_t)K * sizeof(float), stream);

    k_norm_mb<<<K, 64, 0, stream>>>(m, mnb);
    k_prep_x<<<B * H, 256, 0, stream>>>(x, xb);
    k_score_mfma<<<dim3(N / 128, K / 128), 256, 0, stream>>>(xb, mnb, score);
    k_rowstats<<<N / 4, 256, 0, stream>>>(score, idx, cnt);
    k_esum_part<<<dim3(C, S), 256, 0, stream>>>(x, idx, partial);
    k_esum_reduce<<<C, 256, 0, stream>>>(partial, esumT);
    k_newm_t<<<dim3(K / 64, C / 64), 256, 0, stream>>>(m, esumT, cnt, nmt);
    k_out_mfma<<<dim3(N / 128, C / 128), 256, 0, stream>>>(score, nmt, out);
}

// Round 6
// 379.834 us; speedup vs baseline: 1.0079x; 1.0079x over previous
//
#include <hip/hip_runtime.h>
#include <hip/hip_bf16.h>
#include <math.h>

// Problem constants
#define B 8
#define C 512
#define H 64
#define W 64
#define N 32768     // B*H*W tokens
#define K 1024      // clusters
#define HW 4096     // H*W
#define CHW 2097152 // C*H*W
#define S 8         // esum splits (== batch)

typedef unsigned short u16;
typedef __attribute__((ext_vector_type(4))) float f32x4;
typedef __attribute__((ext_vector_type(8))) short bf16x8;

// ws layout (float offsets)
#define MNB_OFF   0                      // K*C u16: bf16 normalized codebook [j][c]
#define IDX_OFF   (MNB_OFF + K*C/2)      // N ints: argmax
#define CNT_OFF   (IDX_OFF + N)          // K floats: counts
#define ESUMT_OFF (CNT_OFF + K)          // C*K floats: esum transposed [c][k]
#define NMT_OFF   (ESUMT_OFF + C*K)      // C*K u16: bf16 new_m transposed [c][j]
#define SCORE_OFF (NMT_OFF + C*K/2)      // N*K u16: bf16 score, then P in-place

static __device__ __forceinline__ u16 f2bf(float f) {
    unsigned int u = __float_as_uint(f);
    u += 0x7fffu + ((u >> 16) & 1u);   // RNE
    return (u16)(u >> 16);
}
static __device__ __forceinline__ float bf2f(unsigned int us) {
    return __uint_as_float(us << 16);
}
static __device__ __forceinline__ unsigned int pack2(float lo, float hi) {
    return (unsigned int)f2bf(lo) | ((unsigned int)f2bf(hi) << 16);
}

static __device__ __forceinline__ void gload_lds16(const void* g, void* l) {
    __builtin_amdgcn_global_load_lds(
        (const __attribute__((address_space(1))) unsigned int*)g,
        (__attribute__((address_space(3))) unsigned int*)l, 16, 0, 0);
}

// ---- normalize codebook rows -> bf16: mnb[j][c] ----
__global__ void k_norm_mb(const float* __restrict__ m, u16* __restrict__ mnb) {
    int j = blockIdx.x;
    int lane = threadIdx.x;  // 64
    const float4* mr = (const float4*)(m + (size_t)j * C);
    float4 a = mr[lane * 2], b = mr[lane * 2 + 1];
    float ss = a.x*a.x + a.y*a.y + a.z*a.z + a.w*a.w
             + b.x*b.x + b.y*b.y + b.z*b.z + b.w*b.w;
#pragma unroll
    for (int o = 32; o >= 1; o >>= 1) ss += __shfl_xor(ss, o);
    float inv = 1.0f / fmaxf(sqrtf(ss), 1e-12f);
    uint4 pk;
    pk.x = pack2(a.x * inv, a.y * inv);
    pk.y = pack2(a.z * inv, a.w * inv);
    pk.z = pack2(b.x * inv, b.y * inv);
    pk.w = pack2(b.z * inv, b.w * inv);
    *(uint4*)(mnb + (size_t)j * C + lane * 8) = pk;
}

// ---- normalize tokens + transpose to token-major bf16: xb[n][c] ----
__global__ void __launch_bounds__(256) k_prep_x(const float* __restrict__ x,
                                                u16* __restrict__ xb) {
    int bh = blockIdx.x;           // b*64 + h
    int b = bh >> 6, h = bh & 63;
    int w  = threadIdx.x & 63;
    int wq = threadIdx.x >> 6;     // 0..3 (channel quarter)
    const float* base = x + (size_t)b * CHW + (size_t)h * W + w;
    float ss = 0.0f;
    for (int ch = wq * 128; ch < wq * 128 + 128; ++ch) {
        float v = base[(size_t)ch * HW];
        ss += v * v;
    }
    __shared__ float red[4][64];
    red[wq][w] = ss;
    __syncthreads();
    float tot = red[0][w] + red[1][w] + red[2][w] + red[3][w];
    float inv = 1.0f / fmaxf(sqrtf(tot), 1e-12f);
    size_t n = (size_t)bh * 64 + w;
    u16* orow = xb + n * C;
    for (int c8 = wq * 128; c8 < wq * 128 + 128; c8 += 8) {
        float v0 = base[(size_t)(c8+0)*HW] * inv;
        float v1 = base[(size_t)(c8+1)*HW] * inv;
        float v2 = base[(size_t)(c8+2)*HW] * inv;
        float v3 = base[(size_t)(c8+3)*HW] * inv;
        float v4 = base[(size_t)(c8+4)*HW] * inv;
        float v5 = base[(size_t)(c8+5)*HW] * inv;
        float v6 = base[(size_t)(c8+6)*HW] * inv;
        float v7 = base[(size_t)(c8+7)*HW] * inv;
        uint4 pk;
        pk.x = pack2(v0, v1); pk.y = pack2(v2, v3);
        pk.z = pack2(v4, v5); pk.w = pack2(v6, v7);
        *(uint4*)&orow[c8] = pk;
    }
}

// ---- GEMM1 (MFMA): score[n][j] = xb[n] . mnb[j], bf16 out ----
// 128x128 tile, BK=64, 4 waves (2x2), 16x16x32 bf16 MFMA, m97 2-barrier structure
__global__ void __launch_bounds__(256) k_score_mfma(
        const u16* __restrict__ xb, const u16* __restrict__ mnb,
        u16* __restrict__ score) {
    __shared__ u16 As[128 * 64];   // [row][k] linear, 128B rows
    __shared__ u16 Bs[128 * 64];
    int tid = threadIdx.x;
    int lane = tid & 63;
    int wid = tid >> 6;            // 0..3
    int wm = wid >> 1, wn = wid & 1;
    int n0 = blockIdx.x * 128;
    int j0 = blockIdx.y * 128;

    f32x4 acc[4][4] = {};

    const u16* a_src = xb + (size_t)(n0 + wid*32 + (lane>>3)) * C + (lane&7)*8;
    const u16* b_src = mnb + (size_t)(j0 + wid*32 + (lane>>3)) * C + (lane&7)*8;

    for (int k0 = 0; k0 < C; k0 += 64) {
#pragma unroll
        for (int is = 0; is < 4; ++is) {
            gload_lds16(a_src + (size_t)is*8*C + k0, As + (wid*32 + is*8)*64);
            gload_lds16(b_src + (size_t)is*8*C + k0, Bs + (wid*32 + is*8)*64);
        }
        __syncthreads();
#pragma unroll
        for (int kh = 0; kh < 2; ++kh) {
            int kk = kh * 32;
            bf16x8 av[4], bv[4];
#pragma unroll
            for (int f = 0; f < 4; ++f) {
                av[f] = *(const bf16x8*)&As[(wm*64 + f*16 + (lane&15))*64 + kk + (lane>>4)*8];
                bv[f] = *(const bf16x8*)&Bs[(wn*64 + f*16 + (lane&15))*64 + kk + (lane>>4)*8];
            }
#pragma unroll
            for (int fm = 0; fm < 4; ++fm)
#pragma unroll
                for (int fn = 0; fn < 4; ++fn)
                    acc[fm][fn] = __builtin_amdgcn_mfma_f32_16x16x32_bf16(
                        av[fm], bv[fn], acc[fm][fn], 0, 0, 0);
        }
        __syncthreads();
    }
    int crow = (lane >> 4) * 4;
    int ccol = lane & 15;
#pragma unroll
    for (int fm = 0; fm < 4; ++fm) {
#pragma unroll
        for (int fn = 0; fn < 4; ++fn) {
            size_t rbase = (size_t)(n0 + wm*64 + fm*16 + crow) * K
                         + (j0 + wn*64 + fn*16 + ccol);
#pragma unroll
            for (int r = 0; r < 4; ++r)
                score[rbase + (size_t)r * K] = f2bf(acc[fm][fn][r]);
        }
    }
}

// ---- row stats + in-place softmax: score -> P = exp(s-max)/sumexp (bf16) ----
__global__ void k_rowstats(u16* __restrict__ score,
                           int* __restrict__ idx, float* __restrict__ counts) {
    int wq = threadIdx.x >> 6, lane = threadIdx.x & 63;
    int n = blockIdx.x * 4 + wq;
    u16* row = score + (size_t)n * K;
    uint4* rp = (uint4*)(row + lane * 16);
    uint4 q0 = rp[0], q1 = rp[1];
    float vals[16];
    unsigned int ws_[8] = {q0.x, q0.y, q0.z, q0.w, q1.x, q1.y, q1.z, q1.w};
#pragma unroll
    for (int e = 0; e < 8; ++e) {
        vals[2 * e]     = bf2f(ws_[e] & 0xffffu);
        vals[2 * e + 1] = bf2f(ws_[e] >> 16);
    }
    float best = -INFINITY; int bj = 0;
#pragma unroll
    for (int e = 0; e < 16; ++e) {
        if (vals[e] > best) { best = vals[e]; bj = lane * 16 + e; }
    }
#pragma unroll
    for (int o = 32; o >= 1; o >>= 1) {
        float ov = __shfl_xor(best, o);
        int   oj = __shfl_xor(bj, o);
        if (ov > best || (ov == best && oj < bj)) { best = ov; bj = oj; }
    }
    float p[16];
    float s = 0.0f;
#pragma unroll
    for (int e = 0; e < 16; ++e) { p[e] = __expf(vals[e] - best); s += p[e]; }
#pragma unroll
    for (int o = 32; o >= 1; o >>= 1) s += __shfl_xor(s, o);
    float sinv = 1.0f / s;
    uint4 o0, o1;
    o0.x = pack2(p[0]*sinv,  p[1]*sinv);
    o0.y = pack2(p[2]*sinv,  p[3]*sinv);
    o0.z = pack2(p[4]*sinv,  p[5]*sinv);
    o0.w = pack2(p[6]*sinv,  p[7]*sinv);
    o1.x = pack2(p[8]*sinv,  p[9]*sinv);
    o1.y = pack2(p[10]*sinv, p[11]*sinv);
    o1.z = pack2(p[12]*sinv, p[13]*sinv);
    o1.w = pack2(p[14]*sinv, p[15]*sinv);
    rp[0] = o0; rp[1] = o1;
    if (lane == 0) {
        idx[n] = bj;
        atomicAdd(&counts[bj], 1.0f);
    }
}

// ---- esum partials: block (ch, s=batch). ALL global loads register-batched
//      up front (8 independent VMEM in flight) then LDS atomics. ----
__global__ void __launch_bounds__(256) k_esum_part(const float* __restrict__ x,
        const int* __restrict__ idx, float* __restrict__ partial) {
    int ch = blockIdx.x;           // 0..511
    int s  = blockIdx.y;           // 0..7  == batch b
    __shared__ float part[K];
    const float* xc = x + (size_t)s * CHW + (size_t)ch * HW;
    const int*   ic = idx + s * HW;
    // issue all 8 loads before any use (ILP: ~4x outstanding vs serialized loop)
    float4 v0_, v1_, v2_, v3_;
    int4   i0_, i1_, i2_, i3_;
    {
        int t0 = threadIdx.x * 4;
        v0_ = *(const float4*)(xc + t0);
        v1_ = *(const float4*)(xc + t0 + 1024);
        v2_ = *(const float4*)(xc + t0 + 2048);
        v3_ = *(const float4*)(xc + t0 + 3072);
        i0_ = *(const int4*)(ic + t0);
        i1_ = *(const int4*)(ic + t0 + 1024);
        i2_ = *(const int4*)(ic + t0 + 2048);
        i3_ = *(const int4*)(ic + t0 + 3072);
    }
    for (int k = threadIdx.x; k < K; k += 256) part[k] = 0.0f;
    __syncthreads();
    atomicAdd(&part[i0_.x], v0_.x); atomicAdd(&part[i0_.y], v0_.y);
    atomicAdd(&part[i0_.z], v0_.z); atomicAdd(&part[i0_.w], v0_.w);
    atomicAdd(&part[i1_.x], v1_.x); atomicAdd(&part[i1_.y], v1_.y);
    atomicAdd(&part[i1_.z], v1_.z); atomicAdd(&part[i1_.w], v1_.w);
    atomicAdd(&part[i2_.x], v2_.x); atomicAdd(&part[i2_.y], v2_.y);
    atomicAdd(&part[i2_.z], v2_.z); atomicAdd(&part[i2_.w], v2_.w);
    atomicAdd(&part[i3_.x], v3_.x); atomicAdd(&part[i3_.y], v3_.y);
    atomicAdd(&part[i3_.z], v3_.z); atomicAdd(&part[i3_.w], v3_.w);
    __syncthreads();
    float* prow = partial + ((size_t)s * C + ch) * K;
    for (int k = threadIdx.x; k < K; k += 256) prow[k] = part[k];
}

// ---- reduce partials -> esumT[c][k] ----
__global__ void __launch_bounds__(256) k_esum_reduce(const float* __restrict__ partial,
        float* __restrict__ esumT) {
    int c = blockIdx.x;            // 0..511
    int k4 = threadIdx.x * 4;      // 0..1020
    float4 acc = make_float4(0.f, 0.f, 0.f, 0.f);
#pragma unroll
    for (int s = 0; s < S; ++s) {
        float4 v = *(const float4*)(partial + ((size_t)s * C + c) * K + k4);
        acc.x += v.x; acc.y += v.y; acc.z += v.z; acc.w += v.w;
    }
    *(float4*)(esumT + (size_t)c * K + k4) = acc;
}

// ---- nmt[c][j] = bf16( 0.999*m[j][c] + 0.001*esumT[c][j]/(cnt[j]+eps) ) ----
__global__ void __launch_bounds__(256) k_newm_t(const float* __restrict__ m,
        const float* __restrict__ esumT, const float* __restrict__ counts,
        u16* __restrict__ nmt) {
    __shared__ float tile[64][65];
    __shared__ float scs[64];
    int jb = blockIdx.x * 64, cb = blockIdx.y * 64;
    int cl = threadIdx.x & 63, jq = threadIdx.x >> 6;   // jq 0..3
#pragma unroll
    for (int r = 0; r < 16; ++r) {
        int jl = jq * 16 + r;
        tile[jl][cl] = m[(size_t)(jb + jl) * C + cb + cl];
    }
    if (threadIdx.x < 64)
        scs[threadIdx.x] = 0.001f / (counts[jb + threadIdx.x] + 1e-6f);
    __syncthreads();
    int crow = threadIdx.x >> 2;        // 0..63 output c row
    int q = threadIdx.x & 3;            // j quarter (16 each)
    const float* erow = esumT + (size_t)(cb + crow) * K + jb + q * 16;
    float4 e0 = *(const float4*)(erow + 0);
    float4 e1 = *(const float4*)(erow + 4);
    float4 e2 = *(const float4*)(erow + 8);
    float4 e3 = *(const float4*)(erow + 12);
    float ev[16] = {e0.x,e0.y,e0.z,e0.w, e1.x,e1.y,e1.z,e1.w,
                    e2.x,e2.y,e2.z,e2.w, e3.x,e3.y,e3.z,e3.w};
    float v[16];
#pragma unroll
    for (int t = 0; t < 16; ++t)
        v[t] = 0.999f * tile[q*16 + t][crow] + ev[t] * scs[q*16 + t];
    uint4 lo, hi;
    lo.x = pack2(v[0], v[1]);   lo.y = pack2(v[2], v[3]);
    lo.z = pack2(v[4], v[5]);   lo.w = pack2(v[6], v[7]);
    hi.x = pack2(v[8], v[9]);   hi.y = pack2(v[10], v[11]);
    hi.z = pack2(v[12], v[13]); hi.w = pack2(v[14], v[15]);
    u16* orow = nmt + (size_t)(cb + crow) * K + jb + q * 16;
    *(uint4*)orow = lo;
    *(uint4*)(orow + 8) = hi;
}

// ---- GEMM2 (MFMA): out[n][c] = P[n] . nmt[c], fp32 NCHW store ----
__global__ void __launch_bounds__(256) k_out_mfma(
        const u16* __restrict__ P, const u16* __restrict__ nmt,
        float* __restrict__ out) {
    __shared__ u16 As[128 * 64];
    __shared__ u16 Bs[128 * 64];
    int tid = threadIdx.x;
    int lane = tid & 63;
    int wid = tid >> 6;
    int wm = wid >> 1, wn = wid & 1;
    int n0 = blockIdx.x * 128;
    int c0 = blockIdx.y * 128;

    f32x4 acc[4][4] = {};

    const u16* a_src = P   + (size_t)(n0 + wid*32 + (lane>>3)) * K + (lane&7)*8;
    const u16* b_src = nmt + (size_t)(c0 + wid*32 + (lane>>3)) * K + (lane&7)*8;

    for (int k0 = 0; k0 < K; k0 += 64) {
#pragma unroll
        for (int is = 0; is < 4; ++is) {
            gload_lds16(a_src + (size_t)is*8*K + k0, As + (wid*32 + is*8)*64);
            gload_lds16(b_src + (size_t)is*8*K + k0, Bs + (wid*32 + is*8)*64);
        }
        __syncthreads();
#pragma unroll
        for (int kh = 0; kh < 2; ++kh) {
            int kk = kh * 32;
            bf16x8 av[4], bv[4];
#pragma unroll
            for (int f = 0; f < 4; ++f) {
                av[f] = *(const bf16x8*)&As[(wm*64 + f*16 + (lane&15))*64 + kk + (lane>>4)*8];
                bv[f] = *(const bf16x8*)&Bs[(wn*64 + f*16 + (lane&15))*64 + kk + (lane>>4)*8];
            }
#pragma unroll
            for (int fm = 0; fm < 4; ++fm)
#pragma unroll
                for (int fn = 0; fn < 4; ++fn)
                    acc[fm][fn] = __builtin_amdgcn_mfma_f32_16x16x32_bf16(
                        av[fm], bv[fn], acc[fm][fn], 0, 0, 0);
        }
        __syncthreads();
    }
    int b = n0 >> 12;
    int hw0 = (n0 & 4095) + wm * 64;
    int crow = (lane >> 4) * 4;
    int ccol = lane & 15;
    float* obase = out + (size_t)b * CHW;
#pragma unroll
    for (int fm = 0; fm < 4; ++fm) {
#pragma unroll
        for (int fn = 0; fn < 4; ++fn) {
            int ch = c0 + wn * 64 + fn * 16 + ccol;
            int hw = hw0 + fm * 16 + crow;
            float4 v = make_float4(acc[fm][fn][0], acc[fm][fn][1],
                                   acc[fm][fn][2], acc[fm][fn][3]);
            *(float4*)&obase[(size_t)ch * HW + hw] = v;
        }
    }
}

extern "C" void kernel_launch(void* const* d_in, const int* in_sizes, int n_in,
                              void* d_out, int out_size, void* d_ws, size_t ws_size,
                              hipStream_t stream) {
    const float* x = (const float*)d_in[0];
    const float* m = (const float*)d_in[1];
    float* out = (float*)d_out;
    float* ws = (float*)d_ws;

    u16*   mnb   = (u16*)(ws + MNB_OFF);
    int*   idx   = (int*)(ws + IDX_OFF);
    float* cnt   = ws + CNT_OFF;
    float* esumT = ws + ESUMT_OFF;
    u16*   nmt   = (u16*)(ws + NMT_OFF);
    u16*   score = (u16*)(ws + SCORE_OFF);
    // d_out scratch: xb (bf16 [N][C], 32MB) in [0,32MB); esum partials (16MB)
    // in [32MB,48MB). Both dead before k_out_mfma fully rewrites d_out.
    u16*   xb      = (u16*)d_out;
    float* partial = (float*)((char*)d_out + (size_t)32 * 1024 * 1024);

    hipMemsetAsync(cnt, 0, (size_t)K * sizeof(float), stream);

    k_norm_mb<<<K, 64, 0, stream>>>(m, mnb);
    k_prep_x<<<B * H, 256, 0, stream>>>(x, xb);
    k_score_mfma<<<dim3(N / 128, K / 128), 256, 0, stream>>>(xb, mnb, score);
    k_rowstats<<<N / 4, 256, 0, stream>>>(score, idx, cnt);
    k_esum_part<<<dim3(C, S), 256, 0, stream>>>(x, idx, partial);
    k_esum_reduce<<<C, 256, 0, stream>>>(partial, esumT);
    k_newm_t<<<dim3(K / 64, C / 64), 256, 0, stream>>>(m, esumT, cnt, nmt);
    k_out_mfma<<<dim3(N / 128, C / 128), 256, 0, stream>>>(score, nmt, out);
}